// Round 8
// baseline (58.151 us; speedup 1.0000x reference)
//
#include <hip/hip_runtime.h>
#include <math.h>

#define OBS 2264
#define ACT 32
#define HID 4096
#define VOX 216
#define PRE (OBS - VOX)    // 2048
#define N4_OBS (OBS / 4)   // 566
#define N4_HID (HID / 4)   // 1024
#define NB 256             // one block per CU (co-resident)
#define NT 512             // 8 waves/block -> co-residency margin
#define RPB 16             // rows per block per GEMV layer (4096/256)
#define RPG 8              // rows per 256-thread group (2 groups)

// ---------------------------------------------------------------------------
// Grid barrier with ZERO cache maintenance:
// - counter ops are RELAXED AGENT-scope atomics (sc1: serialize at the LLC
//   coherence point, no L2 writeback/invalidate — the R5 killer).
// - h0/h1 data also moves via AGENT-scope atomic store/load, so no dirty
//   lines ever sit in a non-coherent XCD L2; no fence is needed.
// - ordering: __syncthreads() lowers to s_waitcnt vmcnt(0) + s_barrier
//   (compiler-guaranteed, m97 asm evidence), so every wave's h-stores are at
//   the LLC before tid 0 issues the arrival fetch_add.
// - s_sleep(12) (~770 cy) polling: ~256 polls/µs chip-wide, no LLC queueing.
// - monotonic counter + next-multiple-of-NB target: valid across 2 barriers
//   and across replays; re-zeroed per launch by a captured hipMemsetAsync.
// - bounded spin: fails loud (absmax error), never hangs the device.
// ---------------------------------------------------------------------------
__device__ __forceinline__ void grid_barrier(unsigned* cnt, int tid) {
    __syncthreads();   // all waves arrived; each wave's vmcnt drained
    if (tid == 0) {
        const unsigned old = __hip_atomic_fetch_add(cnt, 1u, __ATOMIC_RELAXED,
                                                    __HIP_MEMORY_SCOPE_AGENT);
        const unsigned target = (old / NB + 1u) * NB;
        unsigned guard = 0;
        while (__hip_atomic_load(cnt, __ATOMIC_RELAXED,
                                 __HIP_MEMORY_SCOPE_AGENT) < target) {
            __builtin_amdgcn_s_sleep(12);
            if (++guard > (1u << 16)) break;   // ~25 ms cap: fail loud
        }
    }
    __syncthreads();
}

// ---------------------------------------------------------------------------
// Persistent kernel: conv chain + norm (per-block LDS, 1 block/CU so the
// ~2.6 us conv VALU cost is paid once per CU) -> gemv0 -> [gbar] -> gemv1
// -> [gbar] -> gemv_out. 256 blocks x 512 threads.
// ---------------------------------------------------------------------------
__global__ __launch_bounds__(NT) void persistent_kernel(
    const float* __restrict__ x,
    const float* __restrict__ cw0, const float* __restrict__ cb0,
    const float* __restrict__ cw1, const float* __restrict__ cb1,
    const float* __restrict__ cw2, const float* __restrict__ cb2,
    const float* __restrict__ cw3, const float* __restrict__ cb3,
    const float* __restrict__ cw4, const float* __restrict__ cb4,
    const float* __restrict__ cw5, const float* __restrict__ cb5,
    const float* __restrict__ in_shift, const float* __restrict__ in_scale,
    const float* __restrict__ W0, const float* __restrict__ b0,
    const float* __restrict__ W1, const float* __restrict__ b1,
    const float* __restrict__ W2, const float* __restrict__ b2,
    const float* __restrict__ oscale, const float* __restrict__ oshift,
    unsigned* __restrict__ bar,
    float* __restrict__ h0, float* __restrict__ h1,
    float* __restrict__ y)
{
    __shared__ float skw[6][27];
    __shared__ float skb[6];
    __shared__ float vbA[VOX], vbB[VOX];
    __shared__ __align__(16) float su[OBS];
    __shared__ __align__(16) float sh[HID];   // staged h0 (reused for h1)
    __shared__ float part[2][RPG][4];         // [group][row][wave-in-group]
    __shared__ float part8[8];

    const int tid = threadIdx.x;

    // ---- stage conv weights/biases + voxel tail (static idx, no scratch) ----
    if (tid < 162) {
        const float* srcw = tid < 27  ? cw0
                          : tid < 54  ? cw1
                          : tid < 81  ? cw2
                          : tid < 108 ? cw3
                          : tid < 135 ? cw4 : cw5;
        const int base = tid < 27  ? 0
                       : tid < 54  ? 27
                       : tid < 81  ? 54
                       : tid < 108 ? 81
                       : tid < 135 ? 108 : 135;
        reinterpret_cast<float*>(skw)[tid] = srcw[tid - base];
    } else if (tid >= 192 && tid < 198) {
        const float* srcb = tid == 192 ? cb0
                          : tid == 193 ? cb1
                          : tid == 194 ? cb2
                          : tid == 195 ? cb3
                          : tid == 196 ? cb4 : cb5;
        skb[tid - 192] = srcb[0];
    }
    if (tid < VOX) vbA[tid] = x[PRE + tid];
    __syncthreads();

    const int d = tid / 36;
    const int h = (tid / 6) % 6;
    const int w = tid % 6;

#define CONV_LAYER(L, SRC, DST)                                              \
    if (tid < VOX) {                                                         \
        float acc = skb[L];                                                  \
        _Pragma("unroll") for (int kd = 0; kd < 3; ++kd) {                   \
            const int dd = d + kd - 1;                                       \
            if (dd >= 0 && dd <= 5) {                                        \
                _Pragma("unroll") for (int kh = 0; kh < 3; ++kh) {           \
                    const int hh = h + kh - 1;                               \
                    if (hh >= 0 && hh <= 5) {                                \
                        _Pragma("unroll") for (int kw2 = 0; kw2 < 3; ++kw2) {\
                            const int ww = w + kw2 - 1;                      \
                            if (ww >= 0 && ww <= 5)                          \
                                acc += skw[L][kd * 9 + kh * 3 + kw2]         \
                                     * SRC[dd * 36 + hh * 6 + ww];           \
                        }                                                    \
                    }                                                        \
                }                                                            \
            }                                                                \
        }                                                                    \
        DST[tid] = fmaxf(acc, 0.f);                                          \
    }                                                                        \
    __syncthreads();

    CONV_LAYER(0, vbA, vbB)
    CONV_LAYER(1, vbB, vbA)
    CONV_LAYER(2, vbA, vbB)
    CONV_LAYER(3, vbB, vbA)
    CONV_LAYER(4, vbA, vbB)
    CONV_LAYER(5, vbB, vbA)
#undef CONV_LAYER
    // result in vbA

    // ---- input normalization into LDS ----
    for (int i = tid; i < OBS; i += NT) {
        const float val = (i < PRE) ? x[i] : vbA[i - PRE];
        su[i] = (val - in_shift[i]) / (in_scale[i] + 1e-8f);
    }
    __syncthreads();

    const int g = tid >> 8;       // 0..1
    const int t = tid & 255;

    // ---- gemv0: h0 = tanh(W0 . su + b0), 16 rows/block, 8 per group ----
    {
        const int r0 = blockIdx.x * RPB + g * RPG;
        const float4* __restrict__ su4 = reinterpret_cast<const float4*>(su);
        const float4* __restrict__ W4  = reinterpret_cast<const float4*>(W0);
        float accs[RPG];
        #pragma unroll
        for (int r = 0; r < RPG; ++r) accs[r] = 0.f;
        for (int j = t; j < N4_OBS; j += 256) {
            const float4 uv = su4[j];
            #pragma unroll
            for (int r = 0; r < RPG; ++r) {
                const float4 wv = W4[(size_t)(r0 + r) * N4_OBS + j];
                accs[r] += wv.x * uv.x + wv.y * uv.y + wv.z * uv.z + wv.w * uv.w;
            }
        }
        #pragma unroll
        for (int r = 0; r < RPG; ++r) {
            float a = accs[r];
            #pragma unroll
            for (int off = 32; off > 0; off >>= 1) a += __shfl_down(a, off, 64);
            if ((t & 63) == 0) part[g][r][t >> 6] = a;
        }
        __syncthreads();
        if (t < RPG) {
            const float s = part[g][t][0] + part[g][t][1] + part[g][t][2]
                          + part[g][t][3] + b0[r0 + t];
            // AGENT-scope store: lands at the LLC, never dirty in an XCD L2
            __hip_atomic_store(&h0[r0 + t], tanhf(s), __ATOMIC_RELAXED,
                               __HIP_MEMORY_SCOPE_AGENT);
        }
    }

    grid_barrier(bar, tid);

    // ---- stage h0 -> LDS via AGENT (LLC) loads, coalesced ----
    #pragma unroll
    for (int k = 0; k < HID / NT; ++k) {
        const int i = tid + k * NT;
        sh[i] = __hip_atomic_load(&h0[i], __ATOMIC_RELAXED,
                                  __HIP_MEMORY_SCOPE_AGENT);
    }
    __syncthreads();

    // ---- gemv1: h1 = tanh(W1 . sh + b1), 16 rows/block ----
    {
        const int r0 = blockIdx.x * RPB + g * RPG;
        const float4* __restrict__ u4 = reinterpret_cast<const float4*>(sh);
        const float4* __restrict__ W4 = reinterpret_cast<const float4*>(W1);
        float accs[RPG];
        #pragma unroll
        for (int r = 0; r < RPG; ++r) accs[r] = 0.f;
        for (int j = t; j < N4_HID; j += 256) {
            const float4 uv = u4[j];
            #pragma unroll
            for (int r = 0; r < RPG; ++r) {
                const float4 wv = W4[(size_t)(r0 + r) * N4_HID + j];
                accs[r] += wv.x * uv.x + wv.y * uv.y + wv.z * uv.z + wv.w * uv.w;
            }
        }
        #pragma unroll
        for (int r = 0; r < RPG; ++r) {
            float a = accs[r];
            #pragma unroll
            for (int off = 32; off > 0; off >>= 1) a += __shfl_down(a, off, 64);
            if ((t & 63) == 0) part[g][r][t >> 6] = a;
        }
        __syncthreads();
        if (t < RPG) {
            const float s = part[g][t][0] + part[g][t][1] + part[g][t][2]
                          + part[g][t][3] + b1[r0 + t];
            __hip_atomic_store(&h1[r0 + t], tanhf(s), __ATOMIC_RELAXED,
                               __HIP_MEMORY_SCOPE_AGENT);
        }
    }

    grid_barrier(bar, tid);

    // ---- gemv_out: y = (W2 . h1 + b2) * oscale + oshift, blocks 0..31 ----
    if (blockIdx.x < ACT) {
        #pragma unroll
        for (int k = 0; k < HID / NT; ++k) {
            const int i = tid + k * NT;
            sh[i] = __hip_atomic_load(&h1[i], __ATOMIC_RELAXED,
                                      __HIP_MEMORY_SCOPE_AGENT);
        }
        __syncthreads();

        const int row = blockIdx.x;
        const float4* __restrict__ Wr =
            reinterpret_cast<const float4*>(W2 + (size_t)row * HID);
        const float4* __restrict__ u4 = reinterpret_cast<const float4*>(sh);
        float a = 0.f;
        #pragma unroll
        for (int k = 0; k < N4_HID / NT; ++k) {   // 2 float4 per thread
            const float4 wv = Wr[tid + k * NT];
            const float4 uv = u4[tid + k * NT];
            a += wv.x * uv.x + wv.y * uv.y + wv.z * uv.z + wv.w * uv.w;
        }
        #pragma unroll
        for (int off = 32; off > 0; off >>= 1) a += __shfl_down(a, off, 64);
        if ((tid & 63) == 0) part8[tid >> 6] = a;
        __syncthreads();
        if (tid == 0) {
            float s = b2[row];
            #pragma unroll
            for (int i = 0; i < 8; ++i) s += part8[i];
            y[row] = s * oscale[row] + oshift[row];
        }
    }
}

extern "C" void kernel_launch(void* const* d_in, const int* in_sizes, int n_in,
                              void* d_out, int out_size, void* d_ws, size_t ws_size,
                              hipStream_t stream) {
    const float* x = (const float*)d_in[0];

    const float* cw[6];
    const float* cb[6];
    if (in_sizes[2] == 1) {           // interleaved: x, cw0, cb0, cw1, cb1, ...
        for (int i = 0; i < 6; ++i) {
            cw[i] = (const float*)d_in[1 + 2 * i];
            cb[i] = (const float*)d_in[2 + 2 * i];
        }
    } else {                          // grouped: x, cw0..cw5, cb0..cb5
        for (int i = 0; i < 6; ++i) {
            cw[i] = (const float*)d_in[1 + i];
            cb[i] = (const float*)d_in[7 + i];
        }
    }
    const float* W0       = (const float*)d_in[13];
    const float* b0       = (const float*)d_in[14];
    const float* W1       = (const float*)d_in[15];
    const float* b1       = (const float*)d_in[16];
    const float* W2       = (const float*)d_in[17];
    const float* b2       = (const float*)d_in[18];
    const float* in_shift = (const float*)d_in[19];
    const float* in_scale = (const float*)d_in[20];
    const float* oshift   = (const float*)d_in[21];
    const float* oscale   = (const float*)d_in[22];

    // ws layout: [0,64) floats = barrier counter (re-zeroed every launch);
    //            [64, 64+4096) = h0; [64+4096, 64+8192) = h1.
    unsigned* bar = (unsigned*)d_ws;
    float*    wsf = (float*)d_ws;
    float*    h0  = wsf + 64;
    float*    h1  = wsf + 64 + HID;
    float*    y   = (float*)d_out;

    hipMemsetAsync(d_ws, 0, 256, stream);   // capture-safe memset node

    persistent_kernel<<<NB, NT, 0, stream>>>(
        x, cw[0], cb[0], cw[1], cb[1], cw[2], cb[2],
        cw[3], cb[3], cw[4], cb[4], cw[5], cb[5],
        in_shift, in_scale, W0, b0, W1, b1, W2, b2,
        oscale, oshift, bar, h0, h1, y);
}

// Round 9
// 43.910 us; speedup vs baseline: 1.3243x; 1.3243x over previous
//
#include <hip/hip_runtime.h>
#include <math.h>

#define OBS 2264
#define ACT 32
#define HID 4096
#define VOX 216
#define PRE (OBS - VOX)    // 2048
#define N4_OBS (OBS / 4)   // 566
#define N4_HID (HID / 4)   // 1024
#define NB 256             // one block per CU
#define NT 1024            // 16 waves: lower 512 compute, upper 512 prefetch
#define RPB 16             // rows per block per GEMV layer (4096/256)
#define RPG 8              // rows per 256-thread compute group (2 groups)

// ---------------------------------------------------------------------------
// K1: [tid<512]  conv chain + input-norm + GEMV W0 (16 rows/block) + tanh
//     [tid>=512] prefetch this block's 16-row slice of W1 (256 KB) to warm
//                L2/L3, so K2's W1 reads are cache hits. The prefetch runs
//                CONCURRENTLY with conv/gemv0 inside the replay-start window.
// All __syncthreads are top-level and uniform across the whole block; the
// prefetch is paced in 8 segments between them (4 float4 per thread each).
// ---------------------------------------------------------------------------
__global__ __launch_bounds__(NT) void fused0_kernel(
    const float* __restrict__ x,
    const float* __restrict__ cw0, const float* __restrict__ cb0,
    const float* __restrict__ cw1, const float* __restrict__ cb1,
    const float* __restrict__ cw2, const float* __restrict__ cb2,
    const float* __restrict__ cw3, const float* __restrict__ cb3,
    const float* __restrict__ cw4, const float* __restrict__ cb4,
    const float* __restrict__ cw5, const float* __restrict__ cb5,
    const float* __restrict__ in_shift, const float* __restrict__ in_scale,
    const float* __restrict__ W0, const float* __restrict__ b0,
    const float* __restrict__ W1,
    float* __restrict__ h0)
{
    __shared__ float skw[6][27];
    __shared__ float skb[6];
    __shared__ float vbA[VOX], vbB[VOX];
    __shared__ __align__(16) float su[OBS];
    __shared__ float part[2][RPG][4];   // [group][row][wave-in-group]

    const int tid = threadIdx.x;

    // W1 prefetch setup: block b warms rows [b*16, b*16+16) = 16384 float4,
    // 8 segments x 512 threads x 4 float4.
    const float4* __restrict__ W1p =
        reinterpret_cast<const float4*>(W1) + (size_t)blockIdx.x * RPB * N4_HID;
    const int ptid = tid - 512;
    float4 dead = {0.f, 0.f, 0.f, 0.f};
#define PREFETCH_SEG(S)                                                      \
    if (tid >= 512) {                                                        \
        const int base = (S) * 2048 + ptid * 4;                              \
        _Pragma("unroll") for (int k = 0; k < 4; ++k) {                      \
            const float4 v = W1p[base + k];                                  \
            dead.x += v.x; dead.y += v.y; dead.z += v.z; dead.w += v.w;      \
        }                                                                    \
    }

    // ---- stage conv weights/biases + voxel tail (static idx, no scratch) ----
    if (tid < 162) {
        const float* srcw = tid < 27  ? cw0
                          : tid < 54  ? cw1
                          : tid < 81  ? cw2
                          : tid < 108 ? cw3
                          : tid < 135 ? cw4 : cw5;
        const int base = tid < 27  ? 0
                       : tid < 54  ? 27
                       : tid < 81  ? 54
                       : tid < 108 ? 81
                       : tid < 135 ? 108 : 135;
        reinterpret_cast<float*>(skw)[tid] = srcw[tid - base];
    } else if (tid >= 192 && tid < 198) {
        const float* srcb = tid == 192 ? cb0
                          : tid == 193 ? cb1
                          : tid == 194 ? cb2
                          : tid == 195 ? cb3
                          : tid == 196 ? cb4 : cb5;
        skb[tid - 192] = srcb[0];
    }
    if (tid < VOX) vbA[tid] = x[PRE + tid];
    PREFETCH_SEG(0)
    __syncthreads();

    const int d = tid / 36;
    const int h = (tid / 6) % 6;
    const int w = tid % 6;

#define CONV_LAYER(L, SRC, DST)                                              \
    if (tid < VOX) {                                                         \
        float acc = skb[L];                                                  \
        _Pragma("unroll") for (int kd = 0; kd < 3; ++kd) {                   \
            const int dd = d + kd - 1;                                       \
            if (dd >= 0 && dd <= 5) {                                        \
                _Pragma("unroll") for (int kh = 0; kh < 3; ++kh) {           \
                    const int hh = h + kh - 1;                               \
                    if (hh >= 0 && hh <= 5) {                                \
                        _Pragma("unroll") for (int kw2 = 0; kw2 < 3; ++kw2) {\
                            const int ww = w + kw2 - 1;                      \
                            if (ww >= 0 && ww <= 5)                          \
                                acc += skw[L][kd * 9 + kh * 3 + kw2]         \
                                     * SRC[dd * 36 + hh * 6 + ww];           \
                        }                                                    \
                    }                                                        \
                }                                                            \
            }                                                                \
        }                                                                    \
        DST[tid] = fmaxf(acc, 0.f);                                          \
    }                                                                        \
    PREFETCH_SEG(1 + (L))                                                    \
    __syncthreads();

    CONV_LAYER(0, vbA, vbB)
    CONV_LAYER(1, vbB, vbA)
    CONV_LAYER(2, vbA, vbB)
    CONV_LAYER(3, vbB, vbA)
    CONV_LAYER(4, vbA, vbB)
    CONV_LAYER(5, vbB, vbA)
#undef CONV_LAYER
    // result in vbA

    // ---- input normalization into LDS (lower half) / prefetch seg 7 ----
    if (tid < 512) {
        for (int i = tid; i < OBS; i += 512) {
            const float val = (i < PRE) ? x[i] : vbA[i - PRE];
            su[i] = (val - in_shift[i]) / (in_scale[i] + 1e-8f);
        }
    }
    PREFETCH_SEG(7)
    // keep the prefetch loads alive without any store
    asm volatile("" :: "v"(dead.x), "v"(dead.y), "v"(dead.z), "v"(dead.w));
#undef PREFETCH_SEG
    __syncthreads();

    // ---- GEMV W0: tid<512, 16 rows/block, 8 rows per 256-thread group ----
    if (tid < 512) {
        const int g = tid >> 8;     // 0..1
        const int t = tid & 255;
        const int r0 = blockIdx.x * RPB + g * RPG;
        const float4* __restrict__ su4 = reinterpret_cast<const float4*>(su);
        const float4* __restrict__ W4  = reinterpret_cast<const float4*>(W0);

        float accs[RPG];
        #pragma unroll
        for (int r = 0; r < RPG; ++r) accs[r] = 0.f;
        for (int j = t; j < N4_OBS; j += 256) {
            const float4 uv = su4[j];
            #pragma unroll
            for (int r = 0; r < RPG; ++r) {
                const float4 wv = W4[(size_t)(r0 + r) * N4_OBS + j];
                accs[r] += wv.x * uv.x + wv.y * uv.y + wv.z * uv.z + wv.w * uv.w;
            }
        }
        #pragma unroll
        for (int r = 0; r < RPG; ++r) {
            float a = accs[r];
            #pragma unroll
            for (int off = 32; off > 0; off >>= 1) a += __shfl_down(a, off, 64);
            if ((t & 63) == 0) part[g][r][t >> 6] = a;
        }
    }
    __syncthreads();
    if (tid < 512) {
        const int g = tid >> 8;
        const int t = tid & 255;
        const int r0 = blockIdx.x * RPB + g * RPG;
        if (t < RPG) {
            const float s = part[g][t][0] + part[g][t][1] + part[g][t][2]
                          + part[g][t][3] + b0[r0 + t];
            h0[r0 + t] = tanhf(s);
        }
    }
}

// ---------------------------------------------------------------------------
// K2: GEMV W1 [4096,4096] + tanh. 256 blocks x 1024 threads, 16 rows/block.
// h0 staged in LDS. W1 should now be L2/L3-warm from K1's prefetch.
// ---------------------------------------------------------------------------
__global__ __launch_bounds__(NT) void gemv1_kernel(
    const float* __restrict__ W, const float* __restrict__ b,
    const float* __restrict__ u, float* __restrict__ out)
{
    __shared__ __align__(16) float sh[HID];
    __shared__ float part[4][4][4];

    const int tid = threadIdx.x;

    reinterpret_cast<float4*>(sh)[tid] =
        reinterpret_cast<const float4*>(u)[tid];
    __syncthreads();

    const int g = tid >> 8;          // 0..3
    const int t = tid & 255;
    const int r0 = blockIdx.x * RPB + g * 4;
    const float4* __restrict__ u4 = reinterpret_cast<const float4*>(sh);
    const float4* __restrict__ W4 = reinterpret_cast<const float4*>(W);

    float accs[4] = {0.f, 0.f, 0.f, 0.f};
    for (int j = t; j < N4_HID; j += 256) {
        const float4 uv = u4[j];
        #pragma unroll
        for (int r = 0; r < 4; ++r) {
            const float4 wv = W4[(size_t)(r0 + r) * N4_HID + j];
            accs[r] += wv.x * uv.x + wv.y * uv.y + wv.z * uv.z + wv.w * uv.w;
        }
    }
    #pragma unroll
    for (int r = 0; r < 4; ++r) {
        float a = accs[r];
        #pragma unroll
        for (int off = 32; off > 0; off >>= 1) a += __shfl_down(a, off, 64);
        if ((t & 63) == 0) part[g][r][t >> 6] = a;
    }
    __syncthreads();
    if (t < 4) {
        const float s = part[g][t][0] + part[g][t][1] + part[g][t][2]
                      + part[g][t][3] + b[r0 + t];
        out[r0 + t] = tanhf(s);
    }
}

// ---------------------------------------------------------------------------
// K3: final GEMV [32,4096] + output affine. 32 blocks x 1024 threads.
// ---------------------------------------------------------------------------
__global__ __launch_bounds__(NT) void gemv_out_kernel(
    const float* __restrict__ W, const float* __restrict__ b,
    const float* __restrict__ u,
    const float* __restrict__ oscale, const float* __restrict__ oshift,
    float* __restrict__ out)
{
    const int row = blockIdx.x;
    const int tid = threadIdx.x;
    const float4* __restrict__ Wr =
        reinterpret_cast<const float4*>(W + (size_t)row * HID);
    const float4* __restrict__ u4 = reinterpret_cast<const float4*>(u);

    const float4 wv = Wr[tid];
    const float4 uv = u4[tid];
    float a = wv.x * uv.x + wv.y * uv.y + wv.z * uv.z + wv.w * uv.w;

    #pragma unroll
    for (int off = 32; off > 0; off >>= 1) a += __shfl_down(a, off, 64);

    __shared__ float part16[16];
    if ((tid & 63) == 0) part16[tid >> 6] = a;
    __syncthreads();
    if (tid == 0) {
        float s = b[row];
        #pragma unroll
        for (int i = 0; i < 16; ++i) s += part16[i];
        out[row] = s * oscale[row] + oshift[row];
    }
}

extern "C" void kernel_launch(void* const* d_in, const int* in_sizes, int n_in,
                              void* d_out, int out_size, void* d_ws, size_t ws_size,
                              hipStream_t stream) {
    const float* x = (const float*)d_in[0];

    const float* cw[6];
    const float* cb[6];
    if (in_sizes[2] == 1) {           // interleaved: x, cw0, cb0, cw1, cb1, ...
        for (int i = 0; i < 6; ++i) {
            cw[i] = (const float*)d_in[1 + 2 * i];
            cb[i] = (const float*)d_in[2 + 2 * i];
        }
    } else {                          // grouped: x, cw0..cw5, cb0..cb5
        for (int i = 0; i < 6; ++i) {
            cw[i] = (const float*)d_in[1 + i];
            cb[i] = (const float*)d_in[7 + i];
        }
    }
    const float* W0       = (const float*)d_in[13];
    const float* b0       = (const float*)d_in[14];
    const float* W1       = (const float*)d_in[15];
    const float* b1       = (const float*)d_in[16];
    const float* W2       = (const float*)d_in[17];
    const float* b2       = (const float*)d_in[18];
    const float* in_shift = (const float*)d_in[19];
    const float* in_scale = (const float*)d_in[20];
    const float* oshift   = (const float*)d_in[21];
    const float* oscale   = (const float*)d_in[22];

    float* ws = (float*)d_ws;
    float* h0 = ws;            // [0, 4096)
    float* h1 = ws + HID;      // [4096, 8192)
    float* y  = (float*)d_out;

    fused0_kernel<<<NB, NT, 0, stream>>>(
        x, cw[0], cb[0], cw[1], cb[1], cw[2], cb[2],
        cw[3], cb[3], cw[4], cb[4], cw[5], cb[5],
        in_shift, in_scale, W0, b0, W1, h0);

    gemv1_kernel<<<NB, NT, 0, stream>>>(W1, b1, h0, h1);
    gemv_out_kernel<<<ACT, NT, 0, stream>>>(W2, b2, h1, oscale, oshift, y);
}

// Round 10
// 39.191 us; speedup vs baseline: 1.4838x; 1.1204x over previous
//
#include <hip/hip_runtime.h>
#include <math.h>

#define OBS 2264
#define ACT 32
#define HID 4096
#define VOX 216
#define PRE (OBS - VOX)    // 2048
#define N4_OBS (OBS / 4)   // 566
#define N4_HID (HID / 4)   // 1024

// ---------------------------------------------------------------------------
// K1: conv3d chain (6 layers, SAME, ReLU) + input norm -> u[2264]. 1 block.
// ---------------------------------------------------------------------------
__global__ __launch_bounds__(256) void conv_norm_kernel(
    const float* __restrict__ x,
    const float* __restrict__ cw0, const float* __restrict__ cb0,
    const float* __restrict__ cw1, const float* __restrict__ cb1,
    const float* __restrict__ cw2, const float* __restrict__ cb2,
    const float* __restrict__ cw3, const float* __restrict__ cb3,
    const float* __restrict__ cw4, const float* __restrict__ cb4,
    const float* __restrict__ cw5, const float* __restrict__ cb5,
    const float* __restrict__ in_shift, const float* __restrict__ in_scale,
    float* __restrict__ u)
{
    __shared__ float skw[6][27];
    __shared__ float skb[6];
    __shared__ float vbA[VOX], vbB[VOX];

    const int tid = threadIdx.x;

    if (tid < 162) {
        const float* srcw = tid < 27  ? cw0
                          : tid < 54  ? cw1
                          : tid < 81  ? cw2
                          : tid < 108 ? cw3
                          : tid < 135 ? cw4 : cw5;
        const int base = tid < 27  ? 0
                       : tid < 54  ? 27
                       : tid < 81  ? 54
                       : tid < 108 ? 81
                       : tid < 135 ? 108 : 135;
        reinterpret_cast<float*>(skw)[tid] = srcw[tid - base];
    } else if (tid >= 192 && tid < 198) {
        const float* srcb = tid == 192 ? cb0
                          : tid == 193 ? cb1
                          : tid == 194 ? cb2
                          : tid == 195 ? cb3
                          : tid == 196 ? cb4 : cb5;
        skb[tid - 192] = srcb[0];
    }
    if (tid < VOX) vbA[tid] = x[PRE + tid];
    __syncthreads();

    const int d = tid / 36;
    const int h = (tid / 6) % 6;
    const int w = tid % 6;

#define CONV_LAYER(L, SRC, DST)                                              \
    if (tid < VOX) {                                                         \
        float acc = skb[L];                                                  \
        _Pragma("unroll") for (int kd = 0; kd < 3; ++kd) {                   \
            const int dd = d + kd - 1;                                       \
            if (dd >= 0 && dd <= 5) {                                        \
                _Pragma("unroll") for (int kh = 0; kh < 3; ++kh) {           \
                    const int hh = h + kh - 1;                               \
                    if (hh >= 0 && hh <= 5) {                                \
                        _Pragma("unroll") for (int kw2 = 0; kw2 < 3; ++kw2) {\
                            const int ww = w + kw2 - 1;                      \
                            if (ww >= 0 && ww <= 5)                          \
                                acc += skw[L][kd * 9 + kh * 3 + kw2]         \
                                     * SRC[dd * 36 + hh * 6 + ww];           \
                        }                                                    \
                    }                                                        \
                }                                                            \
            }                                                                \
        }                                                                    \
        DST[tid] = fmaxf(acc, 0.f);                                          \
    }                                                                        \
    __syncthreads();

    CONV_LAYER(0, vbA, vbB)
    CONV_LAYER(1, vbB, vbA)
    CONV_LAYER(2, vbA, vbB)
    CONV_LAYER(3, vbB, vbA)
    CONV_LAYER(4, vbA, vbB)
    CONV_LAYER(5, vbB, vbA)
#undef CONV_LAYER

    for (int i = tid; i < OBS; i += 256) {
        const float val = (i < PRE) ? x[i] : vbA[i - PRE];
        u[i] = (val - in_shift[i]) / (in_scale[i] + 1e-8f);
    }
}

__device__ __forceinline__ float dot4(float4 a, float4 b) {
    return a.x * b.x + a.y * b.y + a.z * b.z + a.w * b.w;
}

// ---------------------------------------------------------------------------
// K2: GEMV W0 [4096,2264] + tanh. 2048 blocks x 256, 2 rows/block.
// ALL loads issue in ONE burst of 9 independent dwordx4 per thread
// (2 rows x {t, t+256, masked t+512} + u at the same 3 offsets).
// Tail (566-512=54) handled by masked index, not divergent branch.
// ---------------------------------------------------------------------------
__global__ __launch_bounds__(256) void gemv0_kernel(
    const float* __restrict__ W, const float* __restrict__ b,
    const float* __restrict__ u, float* __restrict__ out)
{
    const int t = threadIdx.x;
    const int row0 = blockIdx.x * 2;
    const float4* __restrict__ u4 = reinterpret_cast<const float4*>(u);
    const float4* __restrict__ Wr0 =
        reinterpret_cast<const float4*>(W) + (size_t)row0 * N4_OBS;
    const float4* __restrict__ Wr1 = Wr0 + N4_OBS;

    const bool  tl = (t < N4_OBS - 512);          // 54 lanes have a 3rd chunk
    const int   j2 = tl ? t + 512 : t;            // safe masked index
    const float m2 = tl ? 1.f : 0.f;

    // ---- single 9-load burst (all independent) ----
    const float4 a0 = Wr0[t];
    const float4 a1 = Wr0[t + 256];
    const float4 a2 = Wr0[j2];
    const float4 c0 = Wr1[t];
    const float4 c1 = Wr1[t + 256];
    const float4 c2 = Wr1[j2];
    const float4 u0 = u4[t];
    const float4 u1 = u4[t + 256];
    const float4 u2 = u4[j2];

    float s0 = dot4(a0, u0) + dot4(a1, u1) + m2 * dot4(a2, u2);
    float s1 = dot4(c0, u0) + dot4(c1, u1) + m2 * dot4(c2, u2);

    #pragma unroll
    for (int off = 32; off > 0; off >>= 1) {
        s0 += __shfl_down(s0, off, 64);
        s1 += __shfl_down(s1, off, 64);
    }
    __shared__ float part[2][4];
    if ((t & 63) == 0) { part[0][t >> 6] = s0; part[1][t >> 6] = s1; }
    __syncthreads();
    if (t < 2) {
        const float s = part[t][0] + part[t][1] + part[t][2] + part[t][3]
                      + b[row0 + t];
        out[row0 + t] = tanhf(s);
    }
}

// ---------------------------------------------------------------------------
// K3: GEMV W1 [4096,4096] + tanh. 2048 blocks x 256, 2 rows/block.
// ONE burst of 12 independent dwordx4 per thread (2 rows x 4 + u x 4).
// ---------------------------------------------------------------------------
__global__ __launch_bounds__(256) void gemv1_kernel(
    const float* __restrict__ W, const float* __restrict__ b,
    const float* __restrict__ u, float* __restrict__ out)
{
    const int t = threadIdx.x;
    const int row0 = blockIdx.x * 2;
    const float4* __restrict__ u4 = reinterpret_cast<const float4*>(u);
    const float4* __restrict__ Wr0 =
        reinterpret_cast<const float4*>(W) + (size_t)row0 * N4_HID;
    const float4* __restrict__ Wr1 = Wr0 + N4_HID;

    // ---- single 12-load burst (all independent) ----
    const float4 a0 = Wr0[t];
    const float4 a1 = Wr0[t + 256];
    const float4 a2 = Wr0[t + 512];
    const float4 a3 = Wr0[t + 768];
    const float4 c0 = Wr1[t];
    const float4 c1 = Wr1[t + 256];
    const float4 c2 = Wr1[t + 512];
    const float4 c3 = Wr1[t + 768];
    const float4 u0 = u4[t];
    const float4 u1 = u4[t + 256];
    const float4 u2 = u4[t + 512];
    const float4 u3 = u4[t + 768];

    float s0 = (dot4(a0, u0) + dot4(a1, u1)) + (dot4(a2, u2) + dot4(a3, u3));
    float s1 = (dot4(c0, u0) + dot4(c1, u1)) + (dot4(c2, u2) + dot4(c3, u3));

    #pragma unroll
    for (int off = 32; off > 0; off >>= 1) {
        s0 += __shfl_down(s0, off, 64);
        s1 += __shfl_down(s1, off, 64);
    }
    __shared__ float part[2][4];
    if ((t & 63) == 0) { part[0][t >> 6] = s0; part[1][t >> 6] = s1; }
    __syncthreads();
    if (t < 2) {
        const float s = part[t][0] + part[t][1] + part[t][2] + part[t][3]
                      + b[row0 + t];
        out[row0 + t] = tanhf(s);
    }
}

// ---------------------------------------------------------------------------
// K4: final GEMV [32,4096] + output affine. 32 blocks x 1024 threads.
// ---------------------------------------------------------------------------
__global__ __launch_bounds__(1024) void gemv_out_kernel(
    const float* __restrict__ W, const float* __restrict__ b,
    const float* __restrict__ u,
    const float* __restrict__ oscale, const float* __restrict__ oshift,
    float* __restrict__ out)
{
    const int row = blockIdx.x;
    const int tid = threadIdx.x;
    const float4* __restrict__ Wr =
        reinterpret_cast<const float4*>(W + (size_t)row * HID);
    const float4* __restrict__ u4 = reinterpret_cast<const float4*>(u);

    const float4 wv = Wr[tid];
    const float4 uv = u4[tid];
    float a = dot4(wv, uv);

    #pragma unroll
    for (int off = 32; off > 0; off >>= 1) a += __shfl_down(a, off, 64);

    __shared__ float part16[16];
    if ((tid & 63) == 0) part16[tid >> 6] = a;
    __syncthreads();
    if (tid == 0) {
        float s = b[row];
        #pragma unroll
        for (int i = 0; i < 16; ++i) s += part16[i];
        out[row] = s * oscale[row] + oshift[row];
    }
}

extern "C" void kernel_launch(void* const* d_in, const int* in_sizes, int n_in,
                              void* d_out, int out_size, void* d_ws, size_t ws_size,
                              hipStream_t stream) {
    const float* x = (const float*)d_in[0];

    const float* cw[6];
    const float* cb[6];
    if (in_sizes[2] == 1) {           // interleaved: x, cw0, cb0, cw1, cb1, ...
        for (int i = 0; i < 6; ++i) {
            cw[i] = (const float*)d_in[1 + 2 * i];
            cb[i] = (const float*)d_in[2 + 2 * i];
        }
    } else {                          // grouped: x, cw0..cw5, cb0..cb5
        for (int i = 0; i < 6; ++i) {
            cw[i] = (const float*)d_in[1 + i];
            cb[i] = (const float*)d_in[7 + i];
        }
    }
    const float* W0       = (const float*)d_in[13];
    const float* b0       = (const float*)d_in[14];
    const float* W1       = (const float*)d_in[15];
    const float* b1       = (const float*)d_in[16];
    const float* W2       = (const float*)d_in[17];
    const float* b2       = (const float*)d_in[18];
    const float* in_shift = (const float*)d_in[19];
    const float* in_scale = (const float*)d_in[20];
    const float* oshift   = (const float*)d_in[21];
    const float* oscale   = (const float*)d_in[22];

    float* ws = (float*)d_ws;
    float* u  = ws;            // [0, 2264) pad to 2304
    float* h0 = ws + 2304;     // [2304, 6400)
    float* h1 = ws + 6400;     // [6400, 10496)
    float* y  = (float*)d_out;

    conv_norm_kernel<<<1, 256, 0, stream>>>(
        x, cw[0], cb[0], cw[1], cb[1], cw[2], cb[2],
        cw[3], cb[3], cw[4], cb[4], cw[5], cb[5],
        in_shift, in_scale, u);

    gemv0_kernel<<<HID / 2, 256, 0, stream>>>(W0, b0, u, h0);
    gemv1_kernel<<<HID / 2, 256, 0, stream>>>(W1, b1, h0, h1);
    gemv_out_kernel<<<ACT, 1024, 0, stream>>>(W2, b2, h1, oscale, oshift, y);
}